// Round 6
// baseline (539.946 us; speedup 1.0000x reference)
//
#include <hip/hip_runtime.h>

// Problem constants: B=2, obj=4, C=256, H=W=48, N=8, HW=2304
#define HH 48
#define WW 48
#define HWP 2304
#define CC 256
#define NB 8
#define QKROW 2305   // 2304 rows + 1 zero pad row (index 2304) for OOB taps

typedef __attribute__((ext_vector_type(8))) short short8;   // 8 x bf16 = 4 VGPR
typedef __attribute__((ext_vector_type(4))) float floatx4;  // MFMA C/D frag

static __device__ __forceinline__ unsigned short f2bf(float f) {
    union { float f; unsigned u; } v; v.f = f;
    unsigned r = v.u + 0x7fffu + ((v.u >> 16) & 1u);        // RNE
    return (unsigned short)(r >> 16);
}
static __device__ __forceinline__ float bf2f(short v) {
    union { unsigned u; float f; } x; x.u = ((unsigned)(unsigned short)v) << 16;
    return x.f;
}

// ---- tiled transpose q/k -> qkT[b][px][c2] bf16 (64x64 tiles via LDS) ------
__global__ __launch_bounds__(256) void k_tr_qk(const float* __restrict__ q,
        const float* __restrict__ kk, unsigned short* __restrict__ qkT) {
    __shared__ float T[64][65];
    const int pg = blockIdx.x, cg = blockIdx.y;
    const int b = blockIdx.z >> 1, src = blockIdx.z & 1;
    const float* s = (src ? kk : q) + (size_t)b * CC * HWP;
    const int tx = threadIdx.x & 63, ty = threadIdx.x >> 6;
#pragma unroll
    for (int i = 0; i < 16; i++) {
        int cl = ty * 16 + i;
        T[cl][tx] = s[(size_t)(cg * 64 + cl) * HWP + pg * 64 + tx];
    }
    __syncthreads();
#pragma unroll
    for (int i = 0; i < 16; i++) {
        int pxl = ty * 16 + i;
        qkT[((size_t)b * QKROW + pg * 64 + pxl) * 512 + src * 256 + cg * 64 + tx]
            = f2bf(T[tx][pxl]);
    }
}

// ---- tiled transpose value -> vT[n][px][c] bf16 ----------------------------
__global__ __launch_bounds__(256) void k_tr_v(const float* __restrict__ v,
                                              unsigned short* __restrict__ vT) {
    __shared__ float T[64][65];
    const int pg = blockIdx.x, cg = blockIdx.y, n = blockIdx.z;
    const float* s = v + (size_t)n * CC * HWP;
    const int tx = threadIdx.x & 63, ty = threadIdx.x >> 6;
#pragma unroll
    for (int i = 0; i < 16; i++) {
        int cl = ty * 16 + i;
        T[cl][tx] = s[(size_t)(cg * 64 + cl) * HWP + pg * 64 + tx];
    }
    __syncthreads();
#pragma unroll
    for (int i = 0; i < 16; i++) {
        int pxl = ty * 16 + i;
        vT[((size_t)n * HWP + pg * 64 + pxl) * 256 + cg * 64 + tx] = f2bf(T[tx][pxl]);
    }
}

// ---- all weight reorders fused (tap-major, bf16) ---------------------------
// segment 0: w1r (1,179,648) | segment 1: wdr (589,824) | segment 2: w2r (73,728)
__global__ __launch_bounds__(256) void k_prep_w(const float* __restrict__ w1,
        const float* __restrict__ dw, const float* __restrict__ w2,
        unsigned short* __restrict__ w1r, unsigned short* __restrict__ wdr,
        unsigned short* __restrict__ w2r) {
    int idx = blockIdx.x * 256 + threadIdx.x;
    if (idx < 1179648) {
        int o = idx / 4608, r = idx % 4608, tap = r / 512, c = r & 511;
        w1r[idx] = f2bf(w1[((size_t)o * 512 + c) * 9 + tap]);
    } else if (idx < 1179648 + 589824) {
        int j = idx - 1179648;
        int o = j / 2304, r = j % 2304, tap = r / 256, c = r & 255;
        wdr[j] = f2bf(dw[((size_t)o * 256 + c) * 9 + tap]);
    } else {
        int j = idx - 1179648 - 589824;
        int o = j / 2304, r = j % 2304, tap = r / 256, c = r & 255;
        w2r[j] = (o < 18) ? f2bf(w2[((size_t)o * 256 + c) * 9 + tap]) : 0;
    }
}

// ---- zero qkT pad rows ------------------------------------------------------
__global__ __launch_bounds__(256) void k_pads(unsigned short* __restrict__ qkT) {
    int t = threadIdx.x;
#pragma unroll
    for (int b = 0; b < 2; b++) {
        qkT[((size_t)b * QKROW + HWP) * 512 + t] = 0;
        qkT[((size_t)b * QKROW + HWP) * 512 + 256 + t] = 0;
    }
}

// ---- feat init: feat[b][px][c] = b1[c] (fp32, conv1 atomically adds) -------
__global__ __launch_bounds__(256) void k_finit(const float* __restrict__ b1,
                                               float* __restrict__ feat) {
    int idx = blockIdx.x * 256 + threadIdx.x;   // 2*2304*256
    feat[idx] = b1[idx & 255];
}

// ---- out init: out[px][n][o] = q[b][o][px] + db[o] (obj-broadcast) ---------
__global__ __launch_bounds__(256) void k_oinit(const float* __restrict__ q,
        const float* __restrict__ db, float* __restrict__ out) {
    __shared__ float T[64][65];
    const int pg = blockIdx.x, cg = blockIdx.y, b = blockIdx.z;
    const int tx = threadIdx.x & 63, ty = threadIdx.x >> 6;
#pragma unroll
    for (int i = 0; i < 16; i++) {
        int cl = ty * 16 + i;
        T[cl][tx] = q[((size_t)b * CC + cg * 64 + cl) * HWP + pg * 64 + tx];
    }
    __syncthreads();
    const float dbo = db[cg * 64 + tx];
#pragma unroll
    for (int i = 0; i < 16; i++) {
        int pxl = ty * 16 + i;
        float val = T[tx][pxl] + dbo;
        float* dst = out + ((size_t)(pg * 64 + pxl) * NB + b * 4) * CC + cg * 64 + tx;
#pragma unroll
        for (int nn = 0; nn < 4; nn++) dst[nn * CC] = val;
    }
}

// ---- conv1: tap-split(9) MFMA GEMM, atomicAdd into feat --------------------
// grid (144 px-tiles, 2 b, 9 taps). 4 waves x (64o x 16px), K=512 per block.
__global__ __launch_bounds__(256) void k_conv1(const unsigned short* __restrict__ qkT,
        const unsigned short* __restrict__ w1r, float* __restrict__ feat) {
    const int tid = threadIdx.x;
    const int pb = blockIdx.x;            // 144
    const int b  = blockIdx.y;
    const int tap = blockIdx.z;           // 9
    const int lane = tid & 63, wv = tid >> 6;
    const int lo = lane & 15, quad = lane >> 4;
    const int pp = pb * 16 + lo;
    const int h = pp / WW, w = pp - (pp / WW) * WW;
    const int dy = tap / 3 - 1, dx = tap % 3 - 1;
    const bool val = (h + dy >= 0) && (h + dy < HH) && (w + dx >= 0) && (w + dx < WW);
    const int row = val ? (pp + dy * WW + dx) : HWP;

    const unsigned short* brow = qkT + ((size_t)b * QKROW + row) * 512 + quad * 8;
    const unsigned short* arow = w1r + (size_t)(wv * 64 + lo) * 4608 + tap * 512 + quad * 8;

    floatx4 acc[4];
#pragma unroll
    for (int mt = 0; mt < 4; mt++) acc[mt] = (floatx4)0.f;

#pragma unroll 4
    for (int ks = 0; ks < 16; ks++) {
        short8 bf = *(const short8*)(brow + ks * 32);
        short8 a0 = *(const short8*)(arow + ks * 32);
        short8 a1 = *(const short8*)(arow + ks * 32 + 16 * 4608);
        short8 a2 = *(const short8*)(arow + ks * 32 + 32 * 4608);
        short8 a3 = *(const short8*)(arow + ks * 32 + 48 * 4608);
        acc[0] = __builtin_amdgcn_mfma_f32_16x16x32_bf16(a0, bf, acc[0], 0, 0, 0);
        acc[1] = __builtin_amdgcn_mfma_f32_16x16x32_bf16(a1, bf, acc[1], 0, 0, 0);
        acc[2] = __builtin_amdgcn_mfma_f32_16x16x32_bf16(a2, bf, acc[2], 0, 0, 0);
        acc[3] = __builtin_amdgcn_mfma_f32_16x16x32_bf16(a3, bf, acc[3], 0, 0, 0);
    }

    float* dst = feat + ((size_t)b * HWP + pp) * 256;
#pragma unroll
    for (int mt = 0; mt < 4; mt++) {
        int o = wv * 64 + mt * 16 + quad * 4;
        atomicAdd(dst + o,     acc[mt][0]);
        atomicAdd(dst + o + 1, acc[mt][1]);
        atomicAdd(dst + o + 2, acc[mt][2]);
        atomicAdd(dst + o + 3, acc[mt][3]);
    }
}

// ---- fcast: featb[b][px][o] = bf16(feat), pad row zero ---------------------
__global__ __launch_bounds__(256) void k_fcast(const float* __restrict__ feat,
                                               unsigned short* __restrict__ featb) {
    const int row = blockIdx.x;           // 0..2304
    const int b = blockIdx.y;
    const int c = threadIdx.x;
    size_t oidx = ((size_t)b * QKROW + row) * 256 + c;
    featb[oidx] = (row < HWP) ? f2bf(feat[((size_t)b * HWP + row) * 256 + c]) : 0;
}

// ---- conv2: tap-split(9) -> fp32 partials off9[t][b][px][32] ---------------
__global__ __launch_bounds__(256) void k_conv2(const unsigned short* __restrict__ featb,
        const unsigned short* __restrict__ w2r, float* __restrict__ off9) {
    const int tid = threadIdx.x;
    const int pb = blockIdx.x;            // 36
    const int b  = blockIdx.y;
    const int tap = blockIdx.z;
    const int lane = tid & 63, wv = tid >> 6;
    const int lo = lane & 15, quad = lane >> 4;
    const int pp = pb * 64 + wv * 16 + lo;
    const int h = pp / WW, w = pp - (pp / WW) * WW;
    const int dy = tap / 3 - 1, dx = tap % 3 - 1;
    const bool val = (h + dy >= 0) && (h + dy < HH) && (w + dx >= 0) && (w + dx < WW);
    const int row = val ? (pp + dy * WW + dx) : HWP;

    const unsigned short* brow = featb + ((size_t)b * QKROW + row) * 256 + quad * 8;
    const unsigned short* arow = w2r + (size_t)lo * 2304 + tap * 256 + quad * 8;

    floatx4 acc[2];
    acc[0] = (floatx4)0.f; acc[1] = (floatx4)0.f;
#pragma unroll
    for (int ks = 0; ks < 8; ks++) {
        short8 bf = *(const short8*)(brow + ks * 32);
        short8 a0 = *(const short8*)(arow + ks * 32);
        short8 a1 = *(const short8*)(arow + ks * 32 + 16 * 2304);
        acc[0] = __builtin_amdgcn_mfma_f32_16x16x32_bf16(a0, bf, acc[0], 0, 0, 0);
        acc[1] = __builtin_amdgcn_mfma_f32_16x16x32_bf16(a1, bf, acc[1], 0, 0, 0);
    }

    float* dst = off9 + (((size_t)tap * 2 + b) * HWP + pp) * 32;
#pragma unroll
    for (int mt = 0; mt < 2; mt++) {
        int o = mt * 16 + quad * 4;
        *(floatx4*)(dst + o) = acc[mt];
    }
}

// ---- osum: off[b][o][px] = sum_t off9 + b2[o]  (o<18) ----------------------
__global__ __launch_bounds__(256) void k_osum(const float* __restrict__ off9,
        const float* __restrict__ b2, float* __restrict__ off) {
    int i = blockIdx.x * 256 + threadIdx.x;        // < 2*18*2304
    int b = i / (18 * HWP);
    int r = i - b * 18 * HWP;
    int o = r / HWP, px = r - o * HWP;
    float s = b2[o];
#pragma unroll
    for (int t = 0; t < 9; t++)
        s += off9[(((size_t)t * 2 + b) * HWP + px) * 32 + o];
    off[i] = s;
}

// ---- deform: tap-group split(3), per-tap LDS staging, MFMA, atomic out -----
// grid (72 px-tiles, 8 n, 3 tap-groups) = 1728 blocks. 4 waves x (64o x 32px).
__global__ __launch_bounds__(256) void k_deform(const unsigned short* __restrict__ vT,
        const float* __restrict__ off, const unsigned short* __restrict__ wdr,
        float* __restrict__ out) {
    __shared__ __align__(16) unsigned short Sl[32 * 256];   // 16 KB

    const int tid = threadIdx.x;
    const int pb  = blockIdx.x;           // 72
    const int n   = blockIdx.y;           // 8
    const int g   = blockIdx.z;           // tap group (3 taps)
    const int b   = n >> 2;
    const int ps  = tid & 31;             // staging pixel
    const int cq  = tid >> 5;             // staging c-eighth (32 c each)
    const int pp  = pb * 32 + ps;
    const int h   = pp / WW, w = pp - (pp / WW) * WW;

    const int lane = tid & 63, wv = tid >> 6;
    const int lo = lane & 15, quad = lane >> 4;

    floatx4 acc[4][2];
#pragma unroll
    for (int mt = 0; mt < 4; mt++)
#pragma unroll
        for (int nt = 0; nt < 2; nt++) acc[mt][nt] = (floatx4)0.f;

    const unsigned short* vTn   = vT + (size_t)n * HWP * 256;
    const unsigned short* aBase = wdr + (size_t)(wv * 64 + lo) * 2304 + quad * 8;

#pragma unroll
    for (int t3 = 0; t3 < 3; t3++) {
        const int tap = g * 3 + t3;
        float dy = off[((size_t)b * 18 + 2 * tap) * HWP + pp];
        float dx = off[((size_t)b * 18 + 2 * tap + 1) * HWP + pp];
        float py = dy + (float)h + (float)(tap / 3 - 1);
        float px = dx + (float)w + (float)(tap % 3 - 1);
        float y0f = floorf(py), x0f = floorf(px);
        int y0 = (int)y0f, x0 = (int)x0f;
        float fy = py - y0f, fx = px - x0f;
        bool y0ok = (y0 >= 0) & (y0 < HH), y1ok = (y0 >= -1) & (y0 < HH - 1);
        bool x0ok = (x0 >= 0) & (x0 < WW), x1ok = (x0 >= -1) & (x0 < WW - 1);
        int y0c = min(max(y0, 0), HH - 1), y1c = min(max(y0 + 1, 0), HH - 1);
        int x0c = min(max(x0, 0), WW - 1), x1c = min(max(x0 + 1, 0), WW - 1);
        int   i0 = y0c * WW + x0c, i1 = y0c * WW + x1c;
        int   i2 = y1c * WW + x0c, i3 = y1c * WW + x1c;
        float w0 = (y0ok && x0ok) ? (1.f - fy) * (1.f - fx) : 0.f;
        float w1 = (y0ok && x1ok) ? (1.f - fy) * fx         : 0.f;
        float w2 = (y1ok && x0ok) ? fy * (1.f - fx)         : 0.f;
        float w3 = (y1ok && x1ok) ? fy * fx                 : 0.f;

        const unsigned short* r0 = vTn + (size_t)i0 * 256;
        const unsigned short* r1 = vTn + (size_t)i1 * 256;
        const unsigned short* r2 = vTn + (size_t)i2 * 256;
        const unsigned short* r3 = vTn + (size_t)i3 * 256;
#pragma unroll
        for (int cg = 0; cg < 4; cg++) {
            int c = cq * 32 + cg * 8;
            short8 a0 = *(const short8*)(r0 + c);
            short8 a1 = *(const short8*)(r1 + c);
            short8 a2 = *(const short8*)(r2 + c);
            short8 a3 = *(const short8*)(r3 + c);
            short8 ov;
#pragma unroll
            for (int j = 0; j < 8; j++) {
                float s = w0 * bf2f(a0[j]) + w1 * bf2f(a1[j])
                        + w2 * bf2f(a2[j]) + w3 * bf2f(a3[j]);
                ov[j] = (short)f2bf(s);
            }
            int gr = (c >> 3) ^ (ps & 7);           // XOR-swizzled 16B granules
            *(short8*)(Sl + ps * 256 + gr * 8) = ov;
        }
        __syncthreads();

        const unsigned short* arow = aBase + tap * 256;
#pragma unroll
        for (int ks = 0; ks < 8; ks++) {
            short8 a0 = *(const short8*)(arow + ks * 32);
            short8 a1 = *(const short8*)(arow + ks * 32 + 16 * 2304);
            short8 a2 = *(const short8*)(arow + ks * 32 + 32 * 2304);
            short8 a3 = *(const short8*)(arow + ks * 32 + 48 * 2304);
            short8 bf[2];
#pragma unroll
            for (int nt = 0; nt < 2; nt++) {
                int rw = nt * 16 + lo;
                int gr = (ks * 4 + quad) ^ (lo & 7);
                bf[nt] = *(const short8*)(Sl + rw * 256 + gr * 8);
            }
#pragma unroll
            for (int nt = 0; nt < 2; nt++) {
                acc[0][nt] = __builtin_amdgcn_mfma_f32_16x16x32_bf16(a0, bf[nt], acc[0][nt], 0, 0, 0);
                acc[1][nt] = __builtin_amdgcn_mfma_f32_16x16x32_bf16(a1, bf[nt], acc[1][nt], 0, 0, 0);
                acc[2][nt] = __builtin_amdgcn_mfma_f32_16x16x32_bf16(a2, bf[nt], acc[2][nt], 0, 0, 0);
                acc[3][nt] = __builtin_amdgcn_mfma_f32_16x16x32_bf16(a3, bf[nt], acc[3][nt], 0, 0, 0);
            }
        }
        __syncthreads();
    }

    // atomic epilogue: out[pq][n][o] += acc   (out pre-initialized to q + db)
#pragma unroll
    for (int mt = 0; mt < 4; mt++) {
        int o = wv * 64 + mt * 16 + quad * 4;
#pragma unroll
        for (int nt = 0; nt < 2; nt++) {
            int pq = pb * 32 + nt * 16 + lo;
            float* dst = out + ((size_t)pq * NB + n) * CC + o;
            atomicAdd(dst,     acc[mt][nt][0]);
            atomicAdd(dst + 1, acc[mt][nt][1]);
            atomicAdd(dst + 2, acc[mt][nt][2]);
            atomicAdd(dst + 3, acc[mt][nt][3]);
        }
    }
}

extern "C" void kernel_launch(void* const* d_in, const int* in_sizes, int n_in,
                              void* d_out, int out_size, void* d_ws, size_t ws_size,
                              hipStream_t stream) {
    const float* q  = (const float*)d_in[0];
    const float* k  = (const float*)d_in[1];
    const float* v  = (const float*)d_in[2];
    const float* w1 = (const float*)d_in[3];
    const float* b1 = (const float*)d_in[4];
    const float* w2 = (const float*)d_in[5];
    const float* b2 = (const float*)d_in[6];
    const float* dw = (const float*)d_in[7];
    const float* db = (const float*)d_in[8];
    float* out = (float*)d_out;

    // ws layout (~31 MB): off | feat | off9 (fp32) || qkT | vT | featb | w1r | wdr | w2r (bf16)
    float* off  = (float*)d_ws;                           //    82,944 f
    float* feat = off + 82944;                            // 1,179,648 f
    float* off9 = feat + 1179648;                         // 1,327,104 f
    unsigned short* qkT   = (unsigned short*)(off9 + 1327104);
    unsigned short* vT    = qkT + 2360320;                // 2*2305*512
    unsigned short* featb = vT + 4718592;                 // 8*2304*256
    unsigned short* w1r   = featb + 1180160;              // 2*2305*256
    unsigned short* wdr   = w1r + 1179648;                // 256*4608
    unsigned short* w2r   = wdr + 589824;                 // 256*2304 (+73728)

    hipLaunchKernelGGL(k_tr_qk, dim3(36, 4, 4),  dim3(256), 0, stream, q, k, qkT);
    hipLaunchKernelGGL(k_tr_v,  dim3(36, 4, 8),  dim3(256), 0, stream, v, vT);
    hipLaunchKernelGGL(k_prep_w,dim3(7200),      dim3(256), 0, stream, w1, dw, w2, w1r, wdr, w2r);
    hipLaunchKernelGGL(k_pads,  dim3(1),         dim3(256), 0, stream, qkT);
    hipLaunchKernelGGL(k_finit, dim3(4608),      dim3(256), 0, stream, b1, feat);
    hipLaunchKernelGGL(k_oinit, dim3(36, 4, 2),  dim3(256), 0, stream, q, db, out);
    hipLaunchKernelGGL(k_conv1, dim3(144, 2, 9), dim3(256), 0, stream, qkT, w1r, feat);
    hipLaunchKernelGGL(k_fcast, dim3(2305, 2),   dim3(256), 0, stream, feat, featb);
    hipLaunchKernelGGL(k_conv2, dim3(36, 2, 9),  dim3(256), 0, stream, featb, w2r, off9);
    hipLaunchKernelGGL(k_osum,  dim3(324),       dim3(256), 0, stream, off9, b2, off);
    hipLaunchKernelGGL(k_deform,dim3(72, 8, 3),  dim3(256), 0, stream, vT, off, wdr, out);
}

// Round 7
// 385.168 us; speedup vs baseline: 1.4018x; 1.4018x over previous
//
#include <hip/hip_runtime.h>

// Problem constants: B=2, obj=4, C=256, H=W=48, N=8, HW=2304
#define HH 48
#define WW 48
#define HWP 2304
#define CC 256
#define NB 8
#define QKROW 2305   // 2304 rows + 1 zero pad row (index 2304) for OOB taps

typedef __attribute__((ext_vector_type(8))) short short8;   // 8 x bf16 = 4 VGPR
typedef __attribute__((ext_vector_type(4))) float floatx4;  // MFMA C/D frag

static __device__ __forceinline__ unsigned short f2bf(float f) {
    union { float f; unsigned u; } v; v.f = f;
    unsigned r = v.u + 0x7fffu + ((v.u >> 16) & 1u);        // RNE
    return (unsigned short)(r >> 16);
}
static __device__ __forceinline__ float bf2f(short v) {
    union { unsigned u; float f; } x; x.u = ((unsigned)(unsigned short)v) << 16;
    return x.f;
}

// ---- tiled transpose q/k -> qkT[b][px][c2] bf16 (64x64 tiles via LDS) ------
__global__ __launch_bounds__(256) void k_tr_qk(const float* __restrict__ q,
        const float* __restrict__ kk, unsigned short* __restrict__ qkT) {
    __shared__ float T[64][65];
    const int pg = blockIdx.x, cg = blockIdx.y;
    const int b = blockIdx.z >> 1, src = blockIdx.z & 1;
    const float* s = (src ? kk : q) + (size_t)b * CC * HWP;
    const int tx = threadIdx.x & 63, ty = threadIdx.x >> 6;
#pragma unroll
    for (int i = 0; i < 16; i++) {
        int cl = ty * 16 + i;
        T[cl][tx] = s[(size_t)(cg * 64 + cl) * HWP + pg * 64 + tx];
    }
    __syncthreads();
#pragma unroll
    for (int i = 0; i < 16; i++) {
        int pxl = ty * 16 + i;
        qkT[((size_t)b * QKROW + pg * 64 + pxl) * 512 + src * 256 + cg * 64 + tx]
            = f2bf(T[tx][pxl]);
    }
}

// ---- tiled transpose value -> vT[n][px][c] bf16 ----------------------------
__global__ __launch_bounds__(256) void k_tr_v(const float* __restrict__ v,
                                              unsigned short* __restrict__ vT) {
    __shared__ float T[64][65];
    const int pg = blockIdx.x, cg = blockIdx.y, n = blockIdx.z;
    const float* s = v + (size_t)n * CC * HWP;
    const int tx = threadIdx.x & 63, ty = threadIdx.x >> 6;
#pragma unroll
    for (int i = 0; i < 16; i++) {
        int cl = ty * 16 + i;
        T[cl][tx] = s[(size_t)(cg * 64 + cl) * HWP + pg * 64 + tx];
    }
    __syncthreads();
#pragma unroll
    for (int i = 0; i < 16; i++) {
        int pxl = ty * 16 + i;
        vT[((size_t)n * HWP + pg * 64 + pxl) * 256 + cg * 64 + tx] = f2bf(T[tx][pxl]);
    }
}

// ---- all weight reorders fused (tap-major, bf16) ---------------------------
__global__ __launch_bounds__(256) void k_prep_w(const float* __restrict__ w1,
        const float* __restrict__ dw, const float* __restrict__ w2,
        unsigned short* __restrict__ w1r, unsigned short* __restrict__ wdr,
        unsigned short* __restrict__ w2r) {
    int idx = blockIdx.x * 256 + threadIdx.x;
    if (idx < 1179648) {
        int o = idx / 4608, r = idx % 4608, tap = r / 512, c = r & 511;
        w1r[idx] = f2bf(w1[((size_t)o * 512 + c) * 9 + tap]);
    } else if (idx < 1179648 + 589824) {
        int j = idx - 1179648;
        int o = j / 2304, r = j % 2304, tap = r / 256, c = r & 255;
        wdr[j] = f2bf(dw[((size_t)o * 256 + c) * 9 + tap]);
    } else {
        int j = idx - 1179648 - 589824;
        int o = j / 2304, r = j % 2304, tap = r / 256, c = r & 255;
        w2r[j] = (o < 18) ? f2bf(w2[((size_t)o * 256 + c) * 9 + tap]) : 0;
    }
}

// ---- zero qkT pad rows ------------------------------------------------------
__global__ __launch_bounds__(256) void k_pads(unsigned short* __restrict__ qkT) {
    int t = threadIdx.x;
#pragma unroll
    for (int b = 0; b < 2; b++) {
        qkT[((size_t)b * QKROW + HWP) * 512 + t] = 0;
        qkT[((size_t)b * QKROW + HWP) * 512 + 256 + t] = 0;
    }
}

// ---- conv1: tap-split(3) MFMA GEMM -> fp32 partials feat3[g][b][px][o] -----
__global__ __launch_bounds__(256) void k_conv1(const unsigned short* __restrict__ qkT,
        const unsigned short* __restrict__ w1r, float* __restrict__ feat3) {
    const int tid = threadIdx.x;
    const int pb = blockIdx.x;            // 144
    const int b  = blockIdx.y;
    const int g  = blockIdx.z;            // tap row (dy = g-1)
    const int lane = tid & 63, wv = tid >> 6;
    const int lo = lane & 15, quad = lane >> 4;
    const int pp = pb * 16 + lo;
    const int h = pp / WW, w = pp - (pp / WW) * WW;

    floatx4 acc[4];
#pragma unroll
    for (int mt = 0; mt < 4; mt++) acc[mt] = (floatx4)0.f;

    const unsigned short* aBase = w1r + (size_t)(wv * 64 + lo) * 4608 + quad * 8;

#pragma unroll
    for (int t3 = 0; t3 < 3; t3++) {
        const int tap = g * 3 + t3;
        const int dy = g - 1, dx = t3 - 1;
        const bool val = (h + dy >= 0) && (h + dy < HH) && (w + dx >= 0) && (w + dx < WW);
        const int row = val ? (pp + dy * WW + dx) : HWP;
        const unsigned short* brow = qkT + ((size_t)b * QKROW + row) * 512 + quad * 8;
        const unsigned short* arow = aBase + tap * 512;
#pragma unroll 4
        for (int ks = 0; ks < 16; ks++) {
            short8 bf = *(const short8*)(brow + ks * 32);
            short8 a0 = *(const short8*)(arow + ks * 32);
            short8 a1 = *(const short8*)(arow + ks * 32 + 16 * 4608);
            short8 a2 = *(const short8*)(arow + ks * 32 + 32 * 4608);
            short8 a3 = *(const short8*)(arow + ks * 32 + 48 * 4608);
            acc[0] = __builtin_amdgcn_mfma_f32_16x16x32_bf16(a0, bf, acc[0], 0, 0, 0);
            acc[1] = __builtin_amdgcn_mfma_f32_16x16x32_bf16(a1, bf, acc[1], 0, 0, 0);
            acc[2] = __builtin_amdgcn_mfma_f32_16x16x32_bf16(a2, bf, acc[2], 0, 0, 0);
            acc[3] = __builtin_amdgcn_mfma_f32_16x16x32_bf16(a3, bf, acc[3], 0, 0, 0);
        }
    }

    float* dst = feat3 + (((size_t)g * 2 + b) * HWP + pp) * 256;
#pragma unroll
    for (int mt = 0; mt < 4; mt++) {
        int o = wv * 64 + mt * 16 + quad * 4;
        *(floatx4*)(dst + o) = acc[mt];
    }
}

// ---- fcast: featb[b][px][o] = bf16(sum_g feat3 + b1), pad row zero ---------
__global__ __launch_bounds__(256) void k_fcast(const float* __restrict__ feat3,
        const float* __restrict__ b1, unsigned short* __restrict__ featb) {
    const int row = blockIdx.x;           // 0..2304
    const int b = blockIdx.y;
    const int c = threadIdx.x;
    size_t oidx = ((size_t)b * QKROW + row) * 256 + c;
    if (row < HWP) {
        float s = feat3[(((size_t)0 * 2 + b) * HWP + row) * 256 + c]
                + feat3[(((size_t)1 * 2 + b) * HWP + row) * 256 + c]
                + feat3[(((size_t)2 * 2 + b) * HWP + row) * 256 + c] + b1[c];
        featb[oidx] = f2bf(s);
    } else {
        featb[oidx] = 0;
    }
}

// ---- conv2: tap-split(9) -> fp32 partials off9[t][b][px][32] ---------------
__global__ __launch_bounds__(256) void k_conv2(const unsigned short* __restrict__ featb,
        const unsigned short* __restrict__ w2r, float* __restrict__ off9) {
    const int tid = threadIdx.x;
    const int pb = blockIdx.x;            // 36
    const int b  = blockIdx.y;
    const int tap = blockIdx.z;
    const int lane = tid & 63, wv = tid >> 6;
    const int lo = lane & 15, quad = lane >> 4;
    const int pp = pb * 64 + wv * 16 + lo;
    const int h = pp / WW, w = pp - (pp / WW) * WW;
    const int dy = tap / 3 - 1, dx = tap % 3 - 1;
    const bool val = (h + dy >= 0) && (h + dy < HH) && (w + dx >= 0) && (w + dx < WW);
    const int row = val ? (pp + dy * WW + dx) : HWP;

    const unsigned short* brow = featb + ((size_t)b * QKROW + row) * 256 + quad * 8;
    const unsigned short* arow = w2r + (size_t)lo * 2304 + tap * 256 + quad * 8;

    floatx4 acc[2];
    acc[0] = (floatx4)0.f; acc[1] = (floatx4)0.f;
#pragma unroll
    for (int ks = 0; ks < 8; ks++) {
        short8 bf = *(const short8*)(brow + ks * 32);
        short8 a0 = *(const short8*)(arow + ks * 32);
        short8 a1 = *(const short8*)(arow + ks * 32 + 16 * 2304);
        acc[0] = __builtin_amdgcn_mfma_f32_16x16x32_bf16(a0, bf, acc[0], 0, 0, 0);
        acc[1] = __builtin_amdgcn_mfma_f32_16x16x32_bf16(a1, bf, acc[1], 0, 0, 0);
    }

    float* dst = off9 + (((size_t)tap * 2 + b) * HWP + pp) * 32;
#pragma unroll
    for (int mt = 0; mt < 2; mt++) {
        int o = mt * 16 + quad * 4;
        *(floatx4*)(dst + o) = acc[mt];
    }
}

// ---- osum: off[b][o][px] = sum_t off9 + b2[o]  (o<18) ----------------------
__global__ __launch_bounds__(256) void k_osum(const float* __restrict__ off9,
        const float* __restrict__ b2, float* __restrict__ off) {
    int i = blockIdx.x * 256 + threadIdx.x;        // < 2*18*2304
    int b = i / (18 * HWP);
    int r = i - b * 18 * HWP;
    int o = r / HWP, px = r - o * HWP;
    float s = b2[o];
#pragma unroll
    for (int t = 0; t < 9; t++)
        s += off9[(((size_t)t * 2 + b) * HWP + px) * 32 + o];
    off[i] = s;
}

// ---- deform: XCD-swizzled, double-buffered LDS, register-prefetch pipeline -
// 1D grid 576: n = bid&7 (XCD affinity for vT[n] L2 residency), pb = bid>>3.
// Per tap: combine prefetched regs -> LDS[buf]; sync; issue tap+1 loads; GEMM.
__global__ __launch_bounds__(256, 3) void k_deform(const unsigned short* __restrict__ vT,
        const float* __restrict__ off, const unsigned short* __restrict__ wdr,
        const float* __restrict__ db, const float* __restrict__ q,
        float* __restrict__ out) {
    __shared__ __align__(16) unsigned short Sl[2][32 * 256];   // 2 x 16 KB

    const int tid = threadIdx.x;
    const int bid = blockIdx.x;           // 576
    const int n   = bid & 7;              // XCD swizzle: same n -> same XCD
    const int pb  = bid >> 3;             // 72 px-tiles
    const int b   = n >> 2;
    const int ps  = tid & 31;             // staging pixel
    const int cq  = tid >> 5;             // staging c-eighth (32 c each)
    const int pp  = pb * 32 + ps;
    const int h   = pp / WW, w = pp - (pp / WW) * WW;

    const int lane = tid & 63, wv = tid >> 6;
    const int lo = lane & 15, quad = lane >> 4;

    floatx4 acc[4][2];
#pragma unroll
    for (int mt = 0; mt < 4; mt++)
#pragma unroll
        for (int nt = 0; nt < 2; nt++) acc[mt][nt] = (floatx4)0.f;

    const unsigned short* vTn   = vT + (size_t)n * HWP * 256;
    const unsigned short* aBase = wdr + (size_t)(wv * 64 + lo) * 2304 + quad * 8;

    // prefetch state: 16 corner loads (4 c-granules x 4 corners) + weights
    short8 P[4][4];
    float  cwt[4];

    auto prefetch = [&](int tap) {
        float dy = off[((size_t)b * 18 + 2 * tap) * HWP + pp];
        float dx = off[((size_t)b * 18 + 2 * tap + 1) * HWP + pp];
        float py = dy + (float)h + (float)(tap / 3 - 1);
        float px = dx + (float)w + (float)(tap % 3 - 1);
        float y0f = floorf(py), x0f = floorf(px);
        int y0 = (int)y0f, x0 = (int)x0f;
        float fy = py - y0f, fx = px - x0f;
        bool y0ok = (y0 >= 0) & (y0 < HH), y1ok = (y0 >= -1) & (y0 < HH - 1);
        bool x0ok = (x0 >= 0) & (x0 < WW), x1ok = (x0 >= -1) & (x0 < WW - 1);
        int y0c = min(max(y0, 0), HH - 1), y1c = min(max(y0 + 1, 0), HH - 1);
        int x0c = min(max(x0, 0), WW - 1), x1c = min(max(x0 + 1, 0), WW - 1);
        const unsigned short* r0 = vTn + (size_t)(y0c * WW + x0c) * 256 + cq * 32;
        const unsigned short* r1 = vTn + (size_t)(y0c * WW + x1c) * 256 + cq * 32;
        const unsigned short* r2 = vTn + (size_t)(y1c * WW + x0c) * 256 + cq * 32;
        const unsigned short* r3 = vTn + (size_t)(y1c * WW + x1c) * 256 + cq * 32;
        cwt[0] = (y0ok && x0ok) ? (1.f - fy) * (1.f - fx) : 0.f;
        cwt[1] = (y0ok && x1ok) ? (1.f - fy) * fx         : 0.f;
        cwt[2] = (y1ok && x0ok) ? fy * (1.f - fx)         : 0.f;
        cwt[3] = (y1ok && x1ok) ? fy * fx                 : 0.f;
#pragma unroll
        for (int cg = 0; cg < 4; cg++) {
            P[cg][0] = *(const short8*)(r0 + cg * 8);
            P[cg][1] = *(const short8*)(r1 + cg * 8);
            P[cg][2] = *(const short8*)(r2 + cg * 8);
            P[cg][3] = *(const short8*)(r3 + cg * 8);
        }
    };

    prefetch(0);
    int buf = 0;

    for (int tap = 0; tap < 9; tap++) {
        // combine prefetched corners -> LDS[buf] (XOR-swizzled 16B granules)
        {
            float w0 = cwt[0], w1 = cwt[1], w2 = cwt[2], w3 = cwt[3];
            unsigned short* sb = &Sl[buf][0];
#pragma unroll
            for (int cg = 0; cg < 4; cg++) {
                short8 ov;
#pragma unroll
                for (int j = 0; j < 8; j++) {
                    float s = w0 * bf2f(P[cg][0][j]) + w1 * bf2f(P[cg][1][j])
                            + w2 * bf2f(P[cg][2][j]) + w3 * bf2f(P[cg][3][j]);
                    ov[j] = (short)f2bf(s);
                }
                int c = cq * 32 + cg * 8;
                int gr = (c >> 3) ^ (ps & 7);
                *(short8*)(sb + ps * 256 + gr * 8) = ov;
            }
        }
        __syncthreads();

        if (tap < 8) prefetch(tap + 1);   // loads land during GEMM below

        const unsigned short* sb = &Sl[buf][0];
        const unsigned short* arow = aBase + tap * 256;
#pragma unroll
        for (int ks = 0; ks < 8; ks++) {
            short8 a0 = *(const short8*)(arow + ks * 32);
            short8 a1 = *(const short8*)(arow + ks * 32 + 16 * 2304);
            short8 a2 = *(const short8*)(arow + ks * 32 + 32 * 2304);
            short8 a3 = *(const short8*)(arow + ks * 32 + 48 * 2304);
            short8 bf[2];
#pragma unroll
            for (int nt = 0; nt < 2; nt++) {
                int rw = nt * 16 + lo;
                int gr = (ks * 4 + quad) ^ (lo & 7);
                bf[nt] = *(const short8*)(sb + rw * 256 + gr * 8);
            }
#pragma unroll
            for (int nt = 0; nt < 2; nt++) {
                acc[0][nt] = __builtin_amdgcn_mfma_f32_16x16x32_bf16(a0, bf[nt], acc[0][nt], 0, 0, 0);
                acc[1][nt] = __builtin_amdgcn_mfma_f32_16x16x32_bf16(a1, bf[nt], acc[1][nt], 0, 0, 0);
                acc[2][nt] = __builtin_amdgcn_mfma_f32_16x16x32_bf16(a2, bf[nt], acc[2][nt], 0, 0, 0);
                acc[3][nt] = __builtin_amdgcn_mfma_f32_16x16x32_bf16(a3, bf[nt], acc[3][nt], 0, 0, 0);
            }
        }
        buf ^= 1;   // double buffer: next write targets other half, no 2nd barrier
    }

    // epilogue: out[p][n][o] = acc + db[o] + q[b][o][p]
#pragma unroll
    for (int mt = 0; mt < 4; mt++) {
        int o = wv * 64 + mt * 16 + quad * 4;
        float d0 = db[o], d1 = db[o + 1], d2 = db[o + 2], d3 = db[o + 3];
#pragma unroll
        for (int nt = 0; nt < 2; nt++) {
            int pq = pb * 32 + nt * 16 + lo;
            floatx4 r = acc[mt][nt];
            r[0] += d0 + q[((size_t)b * CC + o + 0) * HWP + pq];
            r[1] += d1 + q[((size_t)b * CC + o + 1) * HWP + pq];
            r[2] += d2 + q[((size_t)b * CC + o + 2) * HWP + pq];
            r[3] += d3 + q[((size_t)b * CC + o + 3) * HWP + pq];
            *(floatx4*)(out + ((size_t)pq * NB + n) * CC + o) = r;
        }
    }
}

extern "C" void kernel_launch(void* const* d_in, const int* in_sizes, int n_in,
                              void* d_out, int out_size, void* d_ws, size_t ws_size,
                              hipStream_t stream) {
    const float* q  = (const float*)d_in[0];
    const float* k  = (const float*)d_in[1];
    const float* v  = (const float*)d_in[2];
    const float* w1 = (const float*)d_in[3];
    const float* b1 = (const float*)d_in[4];
    const float* w2 = (const float*)d_in[5];
    const float* b2 = (const float*)d_in[6];
    const float* dw = (const float*)d_in[7];
    const float* db = (const float*)d_in[8];
    float* out = (float*)d_out;

    // ws layout (~40 MB): off | feat3 | off9 (fp32) || qkT | vT | featb | w1r | wdr | w2r (bf16)
    float* off   = (float*)d_ws;                          //    82,944 f
    float* feat3 = off + 82944;                           // 3,538,944 f
    float* off9  = feat3 + 3538944;                       // 1,327,104 f
    unsigned short* qkT   = (unsigned short*)(off9 + 1327104);
    unsigned short* vT    = qkT + 2360320;                // 2*2305*512
    unsigned short* featb = vT + 4718592;                 // 8*2304*256
    unsigned short* w1r   = featb + 1180160;              // 2*2305*256
    unsigned short* wdr   = w1r + 1179648;                // 256*4608
    unsigned short* w2r   = wdr + 589824;                 // 256*2304 (+73728)

    hipLaunchKernelGGL(k_tr_qk, dim3(36, 4, 4),  dim3(256), 0, stream, q, k, qkT);
    hipLaunchKernelGGL(k_tr_v,  dim3(36, 4, 8),  dim3(256), 0, stream, v, vT);
    hipLaunchKernelGGL(k_prep_w,dim3(7200),      dim3(256), 0, stream, w1, dw, w2, w1r, wdr, w2r);
    hipLaunchKernelGGL(k_pads,  dim3(1),         dim3(256), 0, stream, qkT);
    hipLaunchKernelGGL(k_conv1, dim3(144, 2, 3), dim3(256), 0, stream, qkT, w1r, feat3);
    hipLaunchKernelGGL(k_fcast, dim3(2305, 2),   dim3(256), 0, stream, feat3, b1, featb);
    hipLaunchKernelGGL(k_conv2, dim3(36, 2, 9),  dim3(256), 0, stream, featb, w2r, off9);
    hipLaunchKernelGGL(k_osum,  dim3(324),       dim3(256), 0, stream, off9, b2, off);
    hipLaunchKernelGGL(k_deform,dim3(576),       dim3(256), 0, stream, vT, off, wdr, db, q, out);
}

// Round 8
// 255.639 us; speedup vs baseline: 2.1121x; 1.5067x over previous
//
#include <hip/hip_runtime.h>

// Problem constants: B=2, obj=4, C=256, H=W=48, N=8, HW=2304
#define HH 48
#define WW 48
#define HWP 2304
#define CC 256
#define NB 8
#define QKROW 2305   // 2304 rows + 1 zero pad row (index 2304) for OOB taps

typedef __attribute__((ext_vector_type(8))) short short8;   // 8 x bf16 = 4 VGPR
typedef __attribute__((ext_vector_type(4))) float floatx4;  // MFMA C/D frag

static __device__ __forceinline__ unsigned short f2bf(float f) {
    union { float f; unsigned u; } v; v.f = f;
    unsigned r = v.u + 0x7fffu + ((v.u >> 16) & 1u);        // RNE
    return (unsigned short)(r >> 16);
}
static __device__ __forceinline__ float bf2f(short v) {
    union { unsigned u; float f; } x; x.u = ((unsigned)(unsigned short)v) << 16;
    return x.f;
}

// ---- tiled transpose q/k -> qkT[b][px][c2] bf16 (64x64 tiles via LDS) ------
__global__ __launch_bounds__(256) void k_tr_qk(const float* __restrict__ q,
        const float* __restrict__ kk, unsigned short* __restrict__ qkT) {
    __shared__ float T[64][65];
    const int pg = blockIdx.x, cg = blockIdx.y;
    const int b = blockIdx.z >> 1, src = blockIdx.z & 1;
    const float* s = (src ? kk : q) + (size_t)b * CC * HWP;
    const int tx = threadIdx.x & 63, ty = threadIdx.x >> 6;
#pragma unroll
    for (int i = 0; i < 16; i++) {
        int cl = ty * 16 + i;
        T[cl][tx] = s[(size_t)(cg * 64 + cl) * HWP + pg * 64 + tx];
    }
    __syncthreads();
#pragma unroll
    for (int i = 0; i < 16; i++) {
        int pxl = ty * 16 + i;
        qkT[((size_t)b * QKROW + pg * 64 + pxl) * 512 + src * 256 + cg * 64 + tx]
            = f2bf(T[tx][pxl]);
    }
}

// ---- tiled transpose value -> vT[n][px][c] bf16 ----------------------------
__global__ __launch_bounds__(256) void k_tr_v(const float* __restrict__ v,
                                              unsigned short* __restrict__ vT) {
    __shared__ float T[64][65];
    const int pg = blockIdx.x, cg = blockIdx.y, n = blockIdx.z;
    const float* s = v + (size_t)n * CC * HWP;
    const int tx = threadIdx.x & 63, ty = threadIdx.x >> 6;
#pragma unroll
    for (int i = 0; i < 16; i++) {
        int cl = ty * 16 + i;
        T[cl][tx] = s[(size_t)(cg * 64 + cl) * HWP + pg * 64 + tx];
    }
    __syncthreads();
#pragma unroll
    for (int i = 0; i < 16; i++) {
        int pxl = ty * 16 + i;
        vT[((size_t)n * HWP + pg * 64 + pxl) * 256 + cg * 64 + tx] = f2bf(T[tx][pxl]);
    }
}

// ---- weight preshuffle into MFMA-fragment order (1KB contiguous frags) -----
// A-operand lane map (16x16x32): lane l holds A[m = l&15][k = (l>>4)*8 + j].
// w1r:  [tap(9)][kk(16)][mtg(16)][l(64)][j(8)]   (K-index = tap*512 + kk*32 + ...)
// wdr:  [tap(9)][kk(8)] [mtg(16)][l(64)][j(8)]   (K-index = tap*256 + ...)
// w2r:  [tap(9)][kk(8)] [mt(2)]  [l(64)][j(8)]   (rows o>=18 zero)
__global__ __launch_bounds__(256) void k_prep_w(const float* __restrict__ w1,
        const float* __restrict__ dw, const float* __restrict__ w2,
        unsigned short* __restrict__ w1r, unsigned short* __restrict__ wdr,
        unsigned short* __restrict__ w2r) {
    int idx = blockIdx.x * 256 + threadIdx.x;
    if (idx < 1179648) {
        int j = idx & 7, l = (idx >> 3) & 63, mtg = (idx >> 9) & 15;
        int kk = (idx >> 13) & 15, tap = idx >> 17;
        int o = mtg * 16 + (l & 15);
        int c2 = kk * 32 + (l >> 4) * 8 + j;
        w1r[idx] = f2bf(w1[((size_t)o * 512 + c2) * 9 + tap]);
    } else if (idx < 1179648 + 589824) {
        int i2 = idx - 1179648;
        int j = i2 & 7, l = (i2 >> 3) & 63, mtg = (i2 >> 9) & 15;
        int kk = (i2 >> 13) & 7, tap = i2 >> 16;
        int o = mtg * 16 + (l & 15);
        int c = kk * 32 + (l >> 4) * 8 + j;
        wdr[i2] = f2bf(dw[((size_t)o * 256 + c) * 9 + tap]);
    } else {
        int i2 = idx - 1179648 - 589824;
        int j = i2 & 7, l = (i2 >> 3) & 63, mt = (i2 >> 9) & 1;
        int kk = (i2 >> 10) & 7, tap = i2 >> 13;
        int o = mt * 16 + (l & 15);
        int c = kk * 32 + (l >> 4) * 8 + j;
        w2r[i2] = (o < 18) ? f2bf(w2[((size_t)o * 256 + c) * 9 + tap]) : 0;
    }
}

// ---- zero qkT pad rows ------------------------------------------------------
__global__ __launch_bounds__(256) void k_pads(unsigned short* __restrict__ qkT) {
    int t = threadIdx.x;
#pragma unroll
    for (int b = 0; b < 2; b++) {
        qkT[((size_t)b * QKROW + HWP) * 512 + t] = 0;
        qkT[((size_t)b * QKROW + HWP) * 512 + 256 + t] = 0;
    }
}

// ---- conv1: tap-split(3) MFMA GEMM -> fp32 partials feat3[g][b][px][o] -----
__global__ __launch_bounds__(256) void k_conv1(const unsigned short* __restrict__ qkT,
        const unsigned short* __restrict__ w1r, float* __restrict__ feat3) {
    const int tid = threadIdx.x;
    const int pb = blockIdx.x;            // 144
    const int b  = blockIdx.y;
    const int g  = blockIdx.z;            // tap row (dy = g-1)
    const int lane = tid & 63, wv = tid >> 6;
    const int lo = lane & 15, quad = lane >> 4;
    const int pp = pb * 16 + lo;
    const int h = pp / WW, w = pp - (pp / WW) * WW;

    floatx4 acc[4];
#pragma unroll
    for (int mt = 0; mt < 4; mt++) acc[mt] = (floatx4)0.f;

#pragma unroll
    for (int t3 = 0; t3 < 3; t3++) {
        const int tap = g * 3 + t3;
        const int dy = g - 1, dx = t3 - 1;
        const bool val = (h + dy >= 0) && (h + dy < HH) && (w + dx >= 0) && (w + dx < WW);
        const int row = val ? (pp + dy * WW + dx) : HWP;
        const unsigned short* brow = qkT + ((size_t)b * QKROW + row) * 512 + quad * 8;
        // preshuffled frags: base for (tap, kk=0, mtg=wv*4)
        const unsigned short* afr = w1r + (((size_t)tap * 16 * 16 + wv * 4) * 64 + lane) * 8;
#pragma unroll 4
        for (int ks = 0; ks < 16; ks++) {
            short8 bf = *(const short8*)(brow + ks * 32);
            const unsigned short* ak = afr + (size_t)ks * 16 * 512;   // kk step = 16 frags
            short8 a0 = *(const short8*)(ak);
            short8 a1 = *(const short8*)(ak + 512);
            short8 a2 = *(const short8*)(ak + 1024);
            short8 a3 = *(const short8*)(ak + 1536);
            acc[0] = __builtin_amdgcn_mfma_f32_16x16x32_bf16(a0, bf, acc[0], 0, 0, 0);
            acc[1] = __builtin_amdgcn_mfma_f32_16x16x32_bf16(a1, bf, acc[1], 0, 0, 0);
            acc[2] = __builtin_amdgcn_mfma_f32_16x16x32_bf16(a2, bf, acc[2], 0, 0, 0);
            acc[3] = __builtin_amdgcn_mfma_f32_16x16x32_bf16(a3, bf, acc[3], 0, 0, 0);
        }
    }

    float* dst = feat3 + (((size_t)g * 2 + b) * HWP + pp) * 256;
#pragma unroll
    for (int mt = 0; mt < 4; mt++) {
        int o = wv * 64 + mt * 16 + quad * 4;
        *(floatx4*)(dst + o) = acc[mt];
    }
}

// ---- fcast: featb[b][px][o] = bf16(sum_g feat3 + b1), pad row zero ---------
__global__ __launch_bounds__(256) void k_fcast(const float* __restrict__ feat3,
        const float* __restrict__ b1, unsigned short* __restrict__ featb) {
    const int row = blockIdx.x;           // 0..2304
    const int b = blockIdx.y;
    const int c = threadIdx.x;
    size_t oidx = ((size_t)b * QKROW + row) * 256 + c;
    if (row < HWP) {
        float s = feat3[(((size_t)0 * 2 + b) * HWP + row) * 256 + c]
                + feat3[(((size_t)1 * 2 + b) * HWP + row) * 256 + c]
                + feat3[(((size_t)2 * 2 + b) * HWP + row) * 256 + c] + b1[c];
        featb[oidx] = f2bf(s);
    } else {
        featb[oidx] = 0;
    }
}

// ---- conv2: tap-split(9) -> fp32 partials off9[t][b][px][32] ---------------
__global__ __launch_bounds__(256) void k_conv2(const unsigned short* __restrict__ featb,
        const unsigned short* __restrict__ w2r, float* __restrict__ off9) {
    const int tid = threadIdx.x;
    const int pb = blockIdx.x;            // 36
    const int b  = blockIdx.y;
    const int tap = blockIdx.z;
    const int lane = tid & 63, wv = tid >> 6;
    const int lo = lane & 15, quad = lane >> 4;
    const int pp = pb * 64 + wv * 16 + lo;
    const int h = pp / WW, w = pp - (pp / WW) * WW;
    const int dy = tap / 3 - 1, dx = tap % 3 - 1;
    const bool val = (h + dy >= 0) && (h + dy < HH) && (w + dx >= 0) && (w + dx < WW);
    const int row = val ? (pp + dy * WW + dx) : HWP;

    const unsigned short* brow = featb + ((size_t)b * QKROW + row) * 256 + quad * 8;
    const unsigned short* afr = w2r + (((size_t)tap * 8 * 2) * 64 + lane) * 8;

    floatx4 acc[2];
    acc[0] = (floatx4)0.f; acc[1] = (floatx4)0.f;
#pragma unroll
    for (int ks = 0; ks < 8; ks++) {
        short8 bf = *(const short8*)(brow + ks * 32);
        const unsigned short* ak = afr + (size_t)ks * 2 * 512;
        short8 a0 = *(const short8*)(ak);
        short8 a1 = *(const short8*)(ak + 512);
        acc[0] = __builtin_amdgcn_mfma_f32_16x16x32_bf16(a0, bf, acc[0], 0, 0, 0);
        acc[1] = __builtin_amdgcn_mfma_f32_16x16x32_bf16(a1, bf, acc[1], 0, 0, 0);
    }

    float* dst = off9 + (((size_t)tap * 2 + b) * HWP + pp) * 32;
#pragma unroll
    for (int mt = 0; mt < 2; mt++) {
        int o = mt * 16 + quad * 4;
        *(floatx4*)(dst + o) = acc[mt];
    }
}

// ---- osum: off[b][o][px] = sum_t off9 + b2[o]  (o<18) ----------------------
__global__ __launch_bounds__(256) void k_osum(const float* __restrict__ off9,
        const float* __restrict__ b2, float* __restrict__ off) {
    int i = blockIdx.x * 256 + threadIdx.x;        // < 2*18*2304
    int b = i / (18 * HWP);
    int r = i - b * 18 * HWP;
    int o = r / HWP, px = r - o * HWP;
    float s = b2[o];
#pragma unroll
    for (int t = 0; t < 9; t++)
        s += off9[(((size_t)t * 2 + b) * HWP + px) * 32 + o];
    off[i] = s;
}

// ---- deform: XCD-swizzled, dbuf LDS, register prefetch, preshuffled A ------
// launch_bounds (256,2): VGPR budget ~256 so P[4][4] (64 VGPR) stays resident.
__global__ __launch_bounds__(256, 2) void k_deform(const unsigned short* __restrict__ vT,
        const float* __restrict__ off, const unsigned short* __restrict__ wdr,
        const float* __restrict__ db, const float* __restrict__ q,
        float* __restrict__ out) {
    __shared__ __align__(16) unsigned short Sl[2][32 * 256];   // 2 x 16 KB

    const int tid = threadIdx.x;
    const int bid = blockIdx.x;           // 576
    const int n   = bid & 7;              // XCD swizzle: same n -> same XCD
    const int pb  = bid >> 3;             // 72 px-tiles
    const int b   = n >> 2;
    const int ps  = tid & 31;             // staging pixel
    const int cq  = tid >> 5;             // staging c-eighth (32 c each)
    const int pp  = pb * 32 + ps;
    const int h   = pp / WW, w = pp - (pp / WW) * WW;

    const int lane = tid & 63, wv = tid >> 6;
    const int lo = lane & 15, quad = lane >> 4;

    floatx4 acc[4][2];
#pragma unroll
    for (int mt = 0; mt < 4; mt++)
#pragma unroll
        for (int nt = 0; nt < 2; nt++) acc[mt][nt] = (floatx4)0.f;

    const unsigned short* vTn = vT + (size_t)n * HWP * 256;

    short8 P[4][4];
    float  cwt[4];

    auto prefetch = [&](int tap) {
        float dy = off[((size_t)b * 18 + 2 * tap) * HWP + pp];
        float dx = off[((size_t)b * 18 + 2 * tap + 1) * HWP + pp];
        float py = dy + (float)h + (float)(tap / 3 - 1);
        float px = dx + (float)w + (float)(tap % 3 - 1);
        float y0f = floorf(py), x0f = floorf(px);
        int y0 = (int)y0f, x0 = (int)x0f;
        float fy = py - y0f, fx = px - x0f;
        bool y0ok = (y0 >= 0) & (y0 < HH), y1ok = (y0 >= -1) & (y0 < HH - 1);
        bool x0ok = (x0 >= 0) & (x0 < WW), x1ok = (x0 >= -1) & (x0 < WW - 1);
        int y0c = min(max(y0, 0), HH - 1), y1c = min(max(y0 + 1, 0), HH - 1);
        int x0c = min(max(x0, 0), WW - 1), x1c = min(max(x0 + 1, 0), WW - 1);
        const unsigned short* r0 = vTn + (size_t)(y0c * WW + x0c) * 256 + cq * 32;
        const unsigned short* r1 = vTn + (size_t)(y0c * WW + x1c) * 256 + cq * 32;
        const unsigned short* r2 = vTn + (size_t)(y1c * WW + x0c) * 256 + cq * 32;
        const unsigned short* r3 = vTn + (size_t)(y1c * WW + x1c) * 256 + cq * 32;
        cwt[0] = (y0ok && x0ok) ? (1.f - fy) * (1.f - fx) : 0.f;
        cwt[1] = (y0ok && x1ok) ? (1.f - fy) * fx         : 0.f;
        cwt[2] = (y1ok && x0ok) ? fy * (1.f - fx)         : 0.f;
        cwt[3] = (y1ok && x1ok) ? fy * fx                 : 0.f;
#pragma unroll
        for (int cg = 0; cg < 4; cg++) {
            P[cg][0] = *(const short8*)(r0 + cg * 8);
            P[cg][1] = *(const short8*)(r1 + cg * 8);
            P[cg][2] = *(const short8*)(r2 + cg * 8);
            P[cg][3] = *(const short8*)(r3 + cg * 8);
        }
    };

    prefetch(0);
    int buf = 0;

    for (int tap = 0; tap < 9; tap++) {
        {
            float w0 = cwt[0], w1 = cwt[1], w2 = cwt[2], w3 = cwt[3];
            unsigned short* sb = &Sl[buf][0];
#pragma unroll
            for (int cg = 0; cg < 4; cg++) {
                short8 ov;
#pragma unroll
                for (int j = 0; j < 8; j++) {
                    float s = w0 * bf2f(P[cg][0][j]) + w1 * bf2f(P[cg][1][j])
                            + w2 * bf2f(P[cg][2][j]) + w3 * bf2f(P[cg][3][j]);
                    ov[j] = (short)f2bf(s);
                }
                int c = cq * 32 + cg * 8;
                int gr = (c >> 3) ^ (ps & 7);
                *(short8*)(sb + ps * 256 + gr * 8) = ov;
            }
        }
        __syncthreads();

        if (tap < 8) prefetch(tap + 1);   // loads land during GEMM below

        const unsigned short* sb = &Sl[buf][0];
        // preshuffled frags: (tap, kk=ks, mtg = wv*4 + mt)
        const unsigned short* afr = wdr + (((size_t)tap * 8 * 16 + wv * 4) * 64 + lane) * 8;
#pragma unroll
        for (int ks = 0; ks < 8; ks++) {
            const unsigned short* ak = afr + (size_t)ks * 16 * 512;
            short8 a0 = *(const short8*)(ak);
            short8 a1 = *(const short8*)(ak + 512);
            short8 a2 = *(const short8*)(ak + 1024);
            short8 a3 = *(const short8*)(ak + 1536);
            short8 bf[2];
#pragma unroll
            for (int nt = 0; nt < 2; nt++) {
                int rw = nt * 16 + lo;
                int gr = (ks * 4 + quad) ^ (lo & 7);
                bf[nt] = *(const short8*)(sb + rw * 256 + gr * 8);
            }
#pragma unroll
            for (int nt = 0; nt < 2; nt++) {
                acc[0][nt] = __builtin_amdgcn_mfma_f32_16x16x32_bf16(a0, bf[nt], acc[0][nt], 0, 0, 0);
                acc[1][nt] = __builtin_amdgcn_mfma_f32_16x16x32_bf16(a1, bf[nt], acc[1][nt], 0, 0, 0);
                acc[2][nt] = __builtin_amdgcn_mfma_f32_16x16x32_bf16(a2, bf[nt], acc[2][nt], 0, 0, 0);
                acc[3][nt] = __builtin_amdgcn_mfma_f32_16x16x32_bf16(a3, bf[nt], acc[3][nt], 0, 0, 0);
            }
        }
        buf ^= 1;
    }

    // epilogue: out[p][n][o] = acc + db[o] + q[b][o][p]
#pragma unroll
    for (int mt = 0; mt < 4; mt++) {
        int o = wv * 64 + mt * 16 + quad * 4;
        float d0 = db[o], d1 = db[o + 1], d2 = db[o + 2], d3 = db[o + 3];
#pragma unroll
        for (int nt = 0; nt < 2; nt++) {
            int pq = pb * 32 + nt * 16 + lo;
            floatx4 r = acc[mt][nt];
            r[0] += d0 + q[((size_t)b * CC + o + 0) * HWP + pq];
            r[1] += d1 + q[((size_t)b * CC + o + 1) * HWP + pq];
            r[2] += d2 + q[((size_t)b * CC + o + 2) * HWP + pq];
            r[3] += d3 + q[((size_t)b * CC + o + 3) * HWP + pq];
            *(floatx4*)(out + ((size_t)pq * NB + n) * CC + o) = r;
        }
    }
}

extern "C" void kernel_launch(void* const* d_in, const int* in_sizes, int n_in,
                              void* d_out, int out_size, void* d_ws, size_t ws_size,
                              hipStream_t stream) {
    const float* q  = (const float*)d_in[0];
    const float* k  = (const float*)d_in[1];
    const float* v  = (const float*)d_in[2];
    const float* w1 = (const float*)d_in[3];
    const float* b1 = (const float*)d_in[4];
    const float* w2 = (const float*)d_in[5];
    const float* b2 = (const float*)d_in[6];
    const float* dw = (const float*)d_in[7];
    const float* db = (const float*)d_in[8];
    float* out = (float*)d_out;

    // ws layout (~40 MB): off | feat3 | off9 (fp32) || qkT | vT | featb | w1r | wdr | w2r (bf16)
    float* off   = (float*)d_ws;                          //    82,944 f
    float* feat3 = off + 82944;                           // 3,538,944 f
    float* off9  = feat3 + 3538944;                       // 1,327,104 f
    unsigned short* qkT   = (unsigned short*)(off9 + 1327104);
    unsigned short* vT    = qkT + 2360320;                // 2*2305*512
    unsigned short* featb = vT + 4718592;                 // 8*2304*256
    unsigned short* w1r   = featb + 1180160;              // 2*2305*256
    unsigned short* wdr   = w1r + 1179648;                // 256*4608 (frag order)
    unsigned short* w2r   = wdr + 589824;                 // 256*2304 (frag order)

    hipLaunchKernelGGL(k_tr_qk, dim3(36, 4, 4),  dim3(256), 0, stream, q, k, qkT);
    hipLaunchKernelGGL(k_tr_v,  dim3(36, 4, 8),  dim3(256), 0, stream, v, vT);
    hipLaunchKernelGGL(k_prep_w,dim3(7200),      dim3(256), 0, stream, w1, dw, w2, w1r, wdr, w2r);
    hipLaunchKernelGGL(k_pads,  dim3(1),         dim3(256), 0, stream, qkT);
    hipLaunchKernelGGL(k_conv1, dim3(144, 2, 3), dim3(256), 0, stream, qkT, w1r, feat3);
    hipLaunchKernelGGL(k_fcast, dim3(2305, 2),   dim3(256), 0, stream, feat3, b1, featb);
    hipLaunchKernelGGL(k_conv2, dim3(36, 2, 9),  dim3(256), 0, stream, featb, w2r, off9);
    hipLaunchKernelGGL(k_osum,  dim3(324),       dim3(256), 0, stream, off9, b2, off);
    hipLaunchKernelGGL(k_deform,dim3(576),       dim3(256), 0, stream, vT, off, wdr, db, q, out);
}